// Round 1
// baseline (186.967 us; speedup 1.0000x reference)
//
#include <hip/hip_runtime.h>
#include <hip/hip_bf16.h>

typedef __attribute__((ext_vector_type(8))) __bf16 bf16x8;
typedef __attribute__((ext_vector_type(4))) float f32x4;
typedef __attribute__((ext_vector_type(4))) float float4v;

#define MFMA(a, b, c) __builtin_amdgcn_mfma_f32_16x16x32_bf16((a), (b), (c), 0, 0, 0)

constexpr int Bc = 2, Sc = 2048, Hc = 16, Dc = 128;
constexpr int HD = Hc * Dc;            // 2048 floats between consecutive seq rows
constexpr float SCALE = 0.0883883476483184405f;  // 1/sqrt(128)
constexpr float NEGF = -30000.0f;      // "minus infinity" that exp() underflows cleanly

__device__ inline bf16x8 load_cvt8(const float* __restrict__ p) {
    float4v a = *(const float4v*)p;
    float4v b = *(const float4v*)(p + 4);
    bf16x8 r;
    r[0] = (__bf16)a[0]; r[1] = (__bf16)a[1]; r[2] = (__bf16)a[2]; r[3] = (__bf16)a[3];
    r[4] = (__bf16)b[0]; r[5] = (__bf16)b[1]; r[6] = (__bf16)b[2]; r[7] = (__bf16)b[3];
    return r;
}

// One wave handles 16 query rows of one (b,h). Block = 4 waves = 4 q-tiles.
__global__ __launch_bounds__(256) void lumen_attn_kernel(
    const float* __restrict__ Q, const float* __restrict__ K,
    const float* __restrict__ V, const float* __restrict__ SLP,
    float* __restrict__ O)
{
    // P exchange buffer, per-wave slice. Stride 56 bf16 = 112 B: 16B-aligned rows,
    // 28-dword row stride -> ds_read_b128 A-frag reads are only 2-way bank aliased (free).
    __shared__ __align__(16) __bf16 p_lds[4][16 * 56];

    const int lane = threadIdx.x & 63;
    const int wid  = threadIdx.x >> 6;
    const int tile = blockIdx.x * 4 + wid;       // 0 .. 4095
    const int qtile = tile & 127;                // S/16 = 128 tiles per (b,h)
    const int bh = tile >> 7;
    const int h  = bh & 15;
    const int b  = bh >> 4;
    const int qt = qtile << 4;                   // first query row of this tile

    const int cl = lane & 15;                    // column-in-16 (MFMA N / A-row)
    const int kg = lane >> 4;                    // 4-lane group (MFMA k-chunk)
    const int r0 = kg << 2;                      // first C-row this lane owns

    const float slope = SLP[h];

    const size_t base = (size_t)b * Sc * HD + (size_t)h * Dc;
    const float* qp = Q + base;
    const float* kp = K + base;
    const float* vp = V + base;
    float*       op = O + base;

    // ---- Q fragments (A operand): lane holds Q[qt+cl][kg*8 .. kg*8+7] per 32-chunk ----
    bf16x8 qf[4];
    {
        const float* qrow = qp + (size_t)(qt + cl) * HD + kg * 8;
        #pragma unroll
        for (int c = 0; c < 4; ++c) qf[c] = load_cvt8(qrow + c * 32);
    }

    f32x4 o_acc[8];
    #pragma unroll
    for (int nn = 0; nn < 8; ++nn) o_acc[nn] = f32x4{0.f, 0.f, 0.f, 0.f};
    float m_r[4] = {NEGF, NEGF, NEGF, NEGF};
    float s_r[4] = {0.f, 0.f, 0.f, 0.f};

    const int kb0    = (qt > 512 ? (qt - 512) : 0) & ~31;  // first 32-key tile
    const int kb_end = (qt + 15) & ~31;                    // last 32-key tile (<= S-32)

    __bf16* pl = p_lds[wid];

    for (int kb = kb0; kb <= kb_end; kb += 32) {
        // ---- S = Q K^T for 16 queries x 32 keys ----
        f32x4 sacc[2];
        sacc[0] = f32x4{0.f, 0.f, 0.f, 0.f};
        sacc[1] = f32x4{0.f, 0.f, 0.f, 0.f};
        #pragma unroll
        for (int n = 0; n < 2; ++n) {
            const float* krow = kp + (size_t)(kb + n * 16 + cl) * HD + kg * 8;
            #pragma unroll
            for (int c = 0; c < 4; ++c)
                sacc[n] = MFMA(qf[c], load_cvt8(krow + c * 32), sacc[n]);
        }

        // ---- online softmax over this 32-key tile ----
        #pragma unroll
        for (int j = 0; j < 4; ++j) {
            const int qi = qt + r0 + j;
            int rel0 = qi - (kb + cl);
            int rel1 = qi - (kb + 16 + cl);
            bool ok0 = ((unsigned)rel0 <= 512u);
            bool ok1 = ((unsigned)rel1 <= 512u);
            float v0 = ok0 ? fmaf(-slope, (float)rel0, sacc[0][j] * SCALE) : NEGF;
            float v1 = ok1 ? fmaf(-slope, (float)rel1, sacc[1][j] * SCALE) : NEGF;

            float tm = fmaxf(v0, v1);
            #pragma unroll
            for (int off = 1; off < 16; off <<= 1)
                tm = fmaxf(tm, __shfl_xor(tm, off));

            float mnew = fmaxf(m_r[j], tm);
            float fsc  = __expf(m_r[j] - mnew);   // exp(0)=1 when both NEGF; underflows to 0 on first real tile
            float p0 = ok0 ? __expf(v0 - mnew) : 0.f;
            float p1 = ok1 ? __expf(v1 - mnew) : 0.f;

            float ps = p0 + p1;
            #pragma unroll
            for (int off = 1; off < 16; off <<= 1)
                ps += __shfl_xor(ps, off);

            s_r[j] = s_r[j] * fsc + ps;
            m_r[j] = mnew;
            #pragma unroll
            for (int nn = 0; nn < 8; ++nn) o_acc[nn][j] *= fsc;

            pl[(r0 + j) * 56 + cl]      = (__bf16)p0;
            pl[(r0 + j) * 56 + 16 + cl] = (__bf16)p1;
        }

        // wave-local cross-lane visibility of P (single wave owns this slice;
        // DS ops from one wave complete in order, just drain the counter)
        asm volatile("s_waitcnt lgkmcnt(0)" ::: "memory");

        // ---- P A-fragment: lane holds P[cl][kg*8 .. kg*8+7] ----
        bf16x8 pa = *(const bf16x8*)(pl + cl * 56 + kg * 8);

        // ---- PV: out[16q x 128d] += P[16x32] * V[32 x 128] ----
        const float* vrow = vp + (size_t)(kb + kg * 8) * HD + cl;
        #pragma unroll
        for (int nn = 0; nn < 8; ++nn) {
            bf16x8 vf;
            #pragma unroll
            for (int i = 0; i < 8; ++i)
                vf[i] = (__bf16)vrow[(size_t)i * HD + nn * 16];
            o_acc[nn] = MFMA(pa, vf, o_acc[nn]);
        }
        asm volatile("" ::: "memory");  // keep next iter's P stores after this iter's P read
    }

    // ---- epilogue: normalize and store fp32 ----
    #pragma unroll
    for (int j = 0; j < 4; ++j) {
        float inv = 1.0f / s_r[j];
        float* orow = op + (size_t)(qt + r0 + j) * HD;
        #pragma unroll
        for (int nn = 0; nn < 8; ++nn)
            orow[nn * 16 + cl] = o_acc[nn][j] * inv;
    }
}

extern "C" void kernel_launch(void* const* d_in, const int* in_sizes, int n_in,
                              void* d_out, int out_size, void* d_ws, size_t ws_size,
                              hipStream_t stream) {
    const float* q   = (const float*)d_in[0];
    const float* k   = (const float*)d_in[1];
    const float* v   = (const float*)d_in[2];
    const float* slp = (const float*)d_in[3];
    float* out = (float*)d_out;

    const int tiles = Bc * Hc * (Sc / 16);   // 4096 waves
    dim3 grid(tiles / 4);                    // 4 waves per 256-thread block
    lumen_attn_kernel<<<grid, dim3(256), 0, stream>>>(q, k, v, slp, out);
}

// Round 3
// 72.262 us; speedup vs baseline: 2.5874x; 2.5874x over previous
//
#include <hip/hip_runtime.h>
#include <hip/hip_bf16.h>

typedef __attribute__((ext_vector_type(8))) __bf16 bf16x8;
typedef __attribute__((ext_vector_type(4))) __bf16 bf16x4;
typedef __attribute__((ext_vector_type(2))) __bf16 bf16x2;
typedef __attribute__((ext_vector_type(4))) float f32x4;

#define MFMA32(a, b, c) __builtin_amdgcn_mfma_f32_16x16x32_bf16((a), (b), (c), 0, 0, 0)

constexpr int Bc = 2, Sc = 2048, Hc = 16, Dc = 128;
constexpr int HD = Hc * Dc;           // floats between consecutive seq rows
constexpr int QB = 128;               // queries per block (8 waves x 16)
constexpr float SCALE = 0.0883883476483184405f;   // 1/sqrt(128)
constexpr float NEGF = -30000.0f;
constexpr int VROW = 520;             // bytes per V pair-row: 128 d * 4B + 8B pad (bank spread)

__device__ inline bf16x8 load_cvt8(const float* p) {
    f32x4 a = *(const f32x4*)p;
    f32x4 b = *(const f32x4*)(p + 4);
    bf16x8 r;
    r[0]=(__bf16)a[0]; r[1]=(__bf16)a[1]; r[2]=(__bf16)a[2]; r[3]=(__bf16)a[3];
    r[4]=(__bf16)b[0]; r[5]=(__bf16)b[1]; r[6]=(__bf16)b[2]; r[7]=(__bf16)b[3];
    return r;
}

// Block: 512 thr = 8 waves; wave w owns q-rows [qb+16w .. +15] of one (b,h).
// K tile: 64x128 bf16, 256B rows, XOR-swizzled (16B unit ^= (k&7)<<4)  [round-2 audited]
// V tile: paired-key layout byte(k,d) = (k>>1)*520 + d*4 + (k&1)*2
//         -> PV B-frag = 4x ds_read_b32, each (V[k][d],V[k+1][d]); 2-way banks (free)
// P tile: per-wave 16x128B rows, XOR-swizzled                        [round-2 audited]
__global__ __launch_bounds__(512, 4) void lumen_attn_kernel(
    const float* __restrict__ Q, const float* __restrict__ K,
    const float* __restrict__ V, const float* __restrict__ SLP,
    float* __restrict__ O)
{
    __shared__ __align__(16) char k_lds[64 * 256];      // 16 KB
    __shared__ __align__(16) char v_lds[32 * VROW];     // 16.25 KB
    __shared__ __align__(16) char p_lds[8][16 * 128];   // 16 KB

    const int tid  = threadIdx.x;
    const int lane = tid & 63;
    const int wid  = tid >> 6;
    const int cl = lane & 15;          // MFMA col / A-row
    const int kg = lane >> 4;          // 4-lane group
    const int r0 = kg << 2;            // first C-row this lane owns

    // XCD-bijective swizzle: 512 blocks = 8 XCDs x 64 contiguous work ids
    const int bid = blockIdx.x;
    const int swz = (bid & 7) * 64 + (bid >> 3);
    const int qb  = (swz & 15) * QB;   // 16 q-blocks per (b,h)
    const int bh  = swz >> 4;
    const int h = bh & 15, b = bh >> 4;

    const float slope = SLP[h];
    const size_t base = (size_t)b * Sc * HD + (size_t)h * Dc;
    const float* qp = Q + base;
    const float* kp = K + base;
    const float* vp = V + base;
    float*       op = O + base;

    const int qw = qb + wid * 16;      // this wave's first q-row

    // ---- Q fragments: lane holds Q[qw+cl][kg*8 + c*32 .. +7] ----
    bf16x8 qf[4];
    {
        const float* qrow = qp + (size_t)(qw + cl) * HD + kg * 8;
        #pragma unroll
        for (int c = 0; c < 4; ++c) qf[c] = load_cvt8(qrow + c * 32);
    }

    f32x4 o_acc[8];
    #pragma unroll
    for (int nn = 0; nn < 8; ++nn) o_acc[nn] = f32x4{0.f, 0.f, 0.f, 0.f};
    float m_r[4] = {NEGF, NEGF, NEGF, NEGF};
    float s_r[4] = {0.f, 0.f, 0.f, 0.f};

    const int kb0    = qb > 512 ? qb - 512 : 0;        // multiple of 64
    const int kb_end = qb + QB - 64;                   // last 64-key tile start

    const int tk = tid >> 4;            // 0..31
    const int td = (tid & 15) * 8;      // staging d0

    char* const pw = p_lds[wid];

    for (int kb = kb0; kb <= kb_end; kb += 64) {
        __syncthreads();   // previous tile's LDS fully consumed

        // ---- cooperative stage (fp32 -> bf16) ----
        // K: rows p*32+tk
        #pragma unroll
        for (int p = 0; p < 2; ++p) {
            const int k = p * 32 + tk;
            bf16x8 k8 = load_cvt8(kp + (size_t)(kb + k) * HD + td);
            *(bf16x8*)(k_lds + k * 256 + ((td * 2) ^ ((k & 7) << 4))) = k8;
        }
        // V: pair-rows (2tk, 2tk+1), interleaved in registers -> 4x ds_write_b64
        {
            bf16x8 va8 = load_cvt8(vp + (size_t)(kb + 2 * tk) * HD + td);
            bf16x8 vb8 = load_cvt8(vp + (size_t)(kb + 2 * tk + 1) * HD + td);
            #pragma unroll
            for (int j = 0; j < 8; j += 2) {
                bf16x4 pk;
                pk[0] = va8[j];     pk[1] = vb8[j];
                pk[2] = va8[j + 1]; pk[3] = vb8[j + 1];
                *(bf16x4*)(v_lds + tk * VROW + (td + j) * 4) = pk;
            }
        }
        __syncthreads();   // staging visible

        // skip tiles fully outside this wave's window
        if (kb > qw + 15 || kb + 63 < qw - 512) continue;

        // ---- S = Q K^T : 16q x 64k ----
        f32x4 sacc[4];
        #pragma unroll
        for (int n = 0; n < 4; ++n) sacc[n] = f32x4{0.f, 0.f, 0.f, 0.f};
        #pragma unroll
        for (int n = 0; n < 4; ++n) {
            const int key = n * 16 + cl;
            const char* kbse = k_lds + key * 256;
            const int sw = (key & 7) << 4;
            #pragma unroll
            for (int c = 0; c < 4; ++c) {
                bf16x8 kf = *(const bf16x8*)(kbse + ((kg * 16 + c * 64) ^ sw));
                sacc[n] = MFMA32(qf[c], kf, sacc[n]);
            }
        }

        // ---- online softmax ----
        #pragma unroll
        for (int j = 0; j < 4; ++j) {
            const int qi = qw + r0 + j;
            float vv[4]; bool ok[4];
            #pragma unroll
            for (int n = 0; n < 4; ++n) {
                int rel = qi - (kb + n * 16 + cl);
                ok[n] = ((unsigned)rel <= 512u);
                vv[n] = ok[n] ? fmaf(-slope, (float)rel, sacc[n][j] * SCALE) : NEGF;
            }
            float tm = fmaxf(fmaxf(vv[0], vv[1]), fmaxf(vv[2], vv[3]));
            #pragma unroll
            for (int off = 1; off < 16; off <<= 1)
                tm = fmaxf(tm, __shfl_xor(tm, off));

            float mnew = fmaxf(m_r[j], tm);
            float fsc  = __expf(m_r[j] - mnew);
            float pv[4], ps = 0.f;
            #pragma unroll
            for (int n = 0; n < 4; ++n) {
                pv[n] = ok[n] ? __expf(vv[n] - mnew) : 0.f;
                ps += pv[n];
            }
            #pragma unroll
            for (int off = 1; off < 16; off <<= 1)
                ps += __shfl_xor(ps, off);

            s_r[j] = s_r[j] * fsc + ps;
            m_r[j] = mnew;
            #pragma unroll
            for (int nn = 0; nn < 8; ++nn) o_acc[nn][j] *= fsc;

            char* prw = pw + (r0 + j) * 128;
            const int swp = ((r0 + j) & 7) << 4;
            #pragma unroll
            for (int n = 0; n < 4; ++n)
                *(__bf16*)(prw + (((n * 16 + cl) * 2) ^ swp)) = (__bf16)pv[n];
        }

        // P stores visible to own wave's reads (wave-local, in-order DS pipe)
        asm volatile("s_waitcnt lgkmcnt(0)" ::: "memory");

        // ---- PV: o[16q x 128d] += P[16x64] * V[64x128] ----
        const int psw = (cl & 7) << 4;
        const int dcol = cl;                      // base d column = nn*16 + cl
        #pragma unroll
        for (int kk = 0; kk < 2; ++kk) {
            bf16x8 pa = *(const bf16x8*)(pw + cl * 128 + ((kk * 64 + kg * 16) ^ psw));
            #pragma unroll
            for (int nn = 0; nn < 8; ++nn) {
                bf16x8 vf;
                #pragma unroll
                for (int i = 0; i < 4; ++i) {
                    bf16x2 pr2 = *(const bf16x2*)(v_lds + (kk * 16 + kg * 4 + i) * VROW
                                                  + (nn * 16 + dcol) * 4);
                    vf[2 * i]     = pr2[0];
                    vf[2 * i + 1] = pr2[1];
                }
                o_acc[nn] = MFMA32(pa, vf, o_acc[nn]);
            }
        }
    }

    // ---- epilogue ----
    #pragma unroll
    for (int j = 0; j < 4; ++j) {
        float inv = 1.0f / s_r[j];
        float* orow = op + (size_t)(qw + r0 + j) * HD;
        #pragma unroll
        for (int nn = 0; nn < 8; ++nn)
            orow[nn * 16 + cl] = o_acc[nn][j] * inv;
    }
}

extern "C" void kernel_launch(void* const* d_in, const int* in_sizes, int n_in,
                              void* d_out, int out_size, void* d_ws, size_t ws_size,
                              hipStream_t stream) {
    const float* q   = (const float*)d_in[0];
    const float* k   = (const float*)d_in[1];
    const float* v   = (const float*)d_in[2];
    const float* slp = (const float*)d_in[3];
    float* out = (float*)d_out;

    dim3 grid(Bc * Hc * (Sc / QB));   // 512 blocks
    lumen_attn_kernel<<<grid, dim3(512), 0, stream>>>(q, k, v, slp, out);
}